// Round 1
// 2377.596 us; speedup vs baseline: 1.5174x; 1.5174x over previous
//
#include <hip/hip_runtime.h>

typedef unsigned short u16;
typedef __bf16 bf16x8 __attribute__((ext_vector_type(8)));
typedef float floatx4 __attribute__((ext_vector_type(4)));
typedef unsigned short u16x8 __attribute__((ext_vector_type(8)));

#define C_  256
#define NTOK 131072                  // B*D*H*W = 8*4*64*64
#define QSCALE 0.17677669529663687f  // 1/sqrt(32)
#define RPB_N 1575                   // (2*4-1)*(2*8-1)*(2*8-1)

// ws: 128 MiB as two bf16 regions of NTOK*256 elems.
// r0: xw -> q (in-place) -> o (in-place) -> oproj (in-place) -> h1 -> h2
// r1: xn
// d_out (134 MB fp32): [k | v] as bf16 halves during attention, then y/out fp32.
#define R1_ELEMS 33554432ull

__device__ __forceinline__ float bf2f(u16 u) {
    return __uint_as_float(((unsigned)u) << 16);
}
__device__ __forceinline__ u16 f2bf(float f) {
    unsigned u = __float_as_uint(f);
    return (u16)((u + 0x7FFFu + ((u >> 16) & 1u)) >> 16);  // RNE
}

// ---------------------------------------------------------- LN1 + partition
// x fp32 -> xw bf16 (window layout)
__global__ __launch_bounds__(256) void ln_part_kernel(
    const float* __restrict__ x, const float* __restrict__ g, const float* __restrict__ bb,
    u16* __restrict__ xw)
{
    const int lane = threadIdx.x & 63;
    const int wave = threadIdx.x >> 6;
    const int t = blockIdx.x * 4 + wave;          // window row: wb*256+n
    const int wb = t >> 8, n = t & 255;
    const int bidx = wb >> 6, hb = (wb >> 3) & 7, wbl = wb & 7;
    const int d = n >> 6, hh = (n >> 3) & 7, ww = n & 7;
    const size_t src = ((((size_t)bidx * 4 + d) * 64 + hb * 8 + hh) * 64 + wbl * 8 + ww) * C_;
    const int c0 = lane * 4;
    float4 raw = *reinterpret_cast<const float4*>(&x[src + c0]);
    float v0 = raw.x, v1 = raw.y, v2 = raw.z, v3 = raw.w;
    float s = v0 + v1 + v2 + v3;
    float sq = v0 * v0 + v1 * v1 + v2 * v2 + v3 * v3;
#pragma unroll
    for (int off = 32; off > 0; off >>= 1) {
        s  += __shfl_xor(s, off, 64);
        sq += __shfl_xor(sq, off, 64);
    }
    const float mean = s * (1.0f / 256.0f);
    const float var  = sq * (1.0f / 256.0f) - mean * mean;
    const float rstd = rsqrtf(var + 1e-5f);
    float4 gr = *reinterpret_cast<const float4*>(&g[c0]);
    float4 br = *reinterpret_cast<const float4*>(&bb[c0]);
    ushort4 outv;
    outv.x = f2bf((v0 - mean) * rstd * gr.x + br.x);
    outv.y = f2bf((v1 - mean) * rstd * gr.y + br.y);
    outv.z = f2bf((v2 - mean) * rstd * gr.z + br.z);
    outv.w = f2bf((v3 - mean) * rstd * gr.w + br.w);
    *reinterpret_cast<ushort4*>(&xw[(size_t)t * C_ + c0]) = outv;
}

// ------------------------------------------------- residual + LN2
// x fp32 + oproj bf16 (window layout) -> y fp32 (d_out, x layout), xn bf16 (x layout)
__global__ __launch_bounds__(256) void resid_ln2_kernel(
    const float* __restrict__ x, const u16* __restrict__ oproj,
    const float* __restrict__ g, const float* __restrict__ bb,
    float* __restrict__ y, u16* __restrict__ xn)
{
    const int lane = threadIdx.x & 63;
    const int wave = threadIdx.x >> 6;
    const int t = blockIdx.x * 4 + wave;          // x-layout token
    const int wpos = t & 63;
    const int h = (t >> 6) & 63;
    const int d = (t >> 12) & 3;
    const int bidx = t >> 14;
    const int wr = (((bidx * 8) + (h >> 3)) * 8 + (wpos >> 3)) * 256
                 + d * 64 + (h & 7) * 8 + (wpos & 7);   // window row
    const int c0 = lane * 4;
    float4 xr = *reinterpret_cast<const float4*>(&x[(size_t)t * C_ + c0]);
    ushort4 pr = *reinterpret_cast<const ushort4*>(&oproj[(size_t)wr * C_ + c0]);
    float v0 = xr.x + bf2f(pr.x);
    float v1 = xr.y + bf2f(pr.y);
    float v2 = xr.z + bf2f(pr.z);
    float v3 = xr.w + bf2f(pr.w);
    float s = v0 + v1 + v2 + v3;
    float sq = v0 * v0 + v1 * v1 + v2 * v2 + v3 * v3;
#pragma unroll
    for (int off = 32; off > 0; off >>= 1) {
        s  += __shfl_xor(s, off, 64);
        sq += __shfl_xor(sq, off, 64);
    }
    const float mean = s * (1.0f / 256.0f);
    const float var  = sq * (1.0f / 256.0f) - mean * mean;
    const float rstd = rsqrtf(var + 1e-5f);
    float4 yv; yv.x = v0; yv.y = v1; yv.z = v2; yv.w = v3;
    *reinterpret_cast<float4*>(&y[(size_t)t * C_ + c0]) = yv;
    float4 gr = *reinterpret_cast<const float4*>(&g[c0]);
    float4 br = *reinterpret_cast<const float4*>(&bb[c0]);
    ushort4 nv;
    nv.x = f2bf((v0 - mean) * rstd * gr.x + br.x);
    nv.y = f2bf((v1 - mean) * rstd * gr.y + br.y);
    nv.z = f2bf((v2 - mean) * rstd * gr.z + br.z);
    nv.w = f2bf((v3 - mean) * rstd * gr.w + br.w);
    *reinterpret_cast<ushort4*>(&xn[(size_t)t * C_ + c0]) = nv;
}

// ----------------------------------------------------------- MFMA bf16 GEMM
// Fixed shape: M=NTOK, N=256, K=256. One block per 128-row strip (full N).
// A: bf16 [M x 256]. Bgf: fp32 natural [256 x ldb], column window [nc0,nc0+256),
// converted to bf16 during in-LDS transpose. bias fp32.
// mode: 0 plain->Cm(bf16), 1 +bias->Cm, 2 +bias+GELU->Cm,
//       5 Cf(fp32) = Cf + acc + bias, 6 Cf = Cf + acc.
// In-place safe (Cm aliasing A region): blocks read only their own 128-row
// strip (all reads before final barrier) and write only that strip.
__global__ __launch_bounds__(256) void gemm256_kernel(
    const u16* __restrict__ A, const float* __restrict__ Bgf, int ldb, int nc0,
    u16* __restrict__ Cm, float* __restrict__ Cf, const float* __restrict__ bias,
    int mode)
{
    __shared__ __align__(16) u16 As[128][40];   // [row][k], padded
    __shared__ __align__(16) u16 Bs[256][40];   // [n][k],  padded (B^T tile)
    const int tid  = threadIdx.x;
    const int lane = tid & 63, wave = tid >> 6;
    const int lr = lane & 15, lq = lane >> 4;
    const int row0 = blockIdx.x * 128;
    const int wm = (wave & 1) * 64;      // m offset within tile
    const int wn = (wave >> 1) * 128;    // n offset within tile

    floatx4 acc[4][8] = {};

    for (int k0 = 0; k0 < 256; k0 += 32) {
        // stage A: 128 rows x 32 k, vectorized bf16
#pragma unroll
        for (int t = 0; t < 2; ++t) {
            int c = tid + t * 256;            // 0..511
            int r = c >> 2, cc = c & 3;
            *reinterpret_cast<float4*>(&As[r][cc * 8]) =
                *reinterpret_cast<const float4*>(&A[(size_t)(row0 + r) * 256 + k0 + cc * 8]);
        }
        // stage B (fp32 -> bf16) with in-LDS transpose: 32 k-rows x 256 n
#pragma unroll
        for (int t = 0; t < 8; ++t) {
            int c = tid + t * 256;            // 0..2047
            int kk = c >> 6, ng = c & 63;     // k-row, n-group of 4
            float4 bv = *reinterpret_cast<const float4*>(
                &Bgf[(size_t)(k0 + kk) * ldb + nc0 + ng * 4]);
            Bs[ng * 4 + 0][kk] = f2bf(bv.x);
            Bs[ng * 4 + 1][kk] = f2bf(bv.y);
            Bs[ng * 4 + 2][kk] = f2bf(bv.z);
            Bs[ng * 4 + 3][kk] = f2bf(bv.w);
        }
        __syncthreads();
        bf16x8 af[4], bfv[8];
#pragma unroll
        for (int mt = 0; mt < 4; ++mt)
            af[mt] = *reinterpret_cast<const bf16x8*>(&As[wm + mt * 16 + lr][lq * 8]);
#pragma unroll
        for (int nt = 0; nt < 8; ++nt)
            bfv[nt] = *reinterpret_cast<const bf16x8*>(&Bs[wn + nt * 16 + lr][lq * 8]);
#pragma unroll
        for (int mt = 0; mt < 4; ++mt)
#pragma unroll
            for (int nt = 0; nt < 8; ++nt)
                acc[mt][nt] = __builtin_amdgcn_mfma_f32_16x16x32_bf16(
                    af[mt], bfv[nt], acc[mt][nt], 0, 0, 0);
        __syncthreads();
    }

#pragma unroll
    for (int mt = 0; mt < 4; ++mt) {
#pragma unroll
        for (int nt = 0; nt < 8; ++nt) {
#pragma unroll
            for (int r = 0; r < 4; ++r) {
                int row = row0 + wm + mt * 16 + lq * 4 + r;
                int col = wn + nt * 16 + lr;
                size_t idx = (size_t)row * 256 + col;
                float v = acc[mt][nt][r];
                if (mode == 1 || mode == 2 || mode == 5) v += bias[col];
                if (mode == 2) v = 0.5f * v * (1.0f + erff(v * 0.70710678118654752f));
                if (mode >= 5) {
                    v += Cf[idx];          // fp32 accumulate in place (own element)
                    Cf[idx] = v;
                } else {
                    Cm[idx] = f2bf(v);
                }
            }
        }
    }
}

// -------------------------------------------------------------- attention
// MFMA version. block = (window wb, depth-slice i); 8 heads sequential.
// 64 q x 192 keys, hd=32. 4 waves: wave w owns q-rows [16w, 16w+16).
// Per head, per wave:
//   QK^T: 12x mfma_f32_16x16x32_bf16 (A=qh rows, B=kt as [key][c] = B^T)
//   scale+bias in-register (rel idx hoisted, bias column staged in LDS)
//   wave-parallel softmax: in-lane reduce over 12 tiles + shfl_xor over 16 lanes
//   P -> sp (bf16), PV: 12x mfma (A=sp rows, B=vtt as [d][key] = V^T)
// LDS: qh 5120 + kt 15360 + vtt 12800 + sp 25600 + bias 6304 = 65184 B.
__global__ __launch_bounds__(256) void attn_kernel(
    u16* __restrict__ qo, const u16* __restrict__ kb, const u16* __restrict__ vb,
    const float* __restrict__ rpbp)
{
    __shared__ __align__(16) u16 qh[64][40];     // [q][c]
    __shared__ __align__(16) u16 kt[192][40];    // [key][c]
    __shared__ __align__(16) u16 vtt[32][200];   // [d][key]  (V^T)
    __shared__ __align__(16) u16 sp[64][200];    // [q][key]  (P, bf16)
    __shared__ float biasld[RPB_N + 1];          // rpb column for head h

    const int wb = blockIdx.x >> 2;
    const int i  = blockIdx.x & 3;
    const int tid = threadIdx.x;
    const int lane = tid & 63, wave = tid >> 6;
    const int lr = lane & 15, lq = lane >> 4;
    const size_t qbase = ((size_t)(wb * 256 + i * 64)) * C_;

    // hoisted rel-position indices for this lane's 48 score cells:
    // q = 16*wave + lq*4 + r, kl = t*16 + lr   (head-independent)
    int relb[12][4];
    {
        const int q0 = wave * 16 + lq * 4;
#pragma unroll
        for (int r = 0; r < 4; ++r) {
            const int q = q0 + r;
            const int hq = q >> 3, wq_ = q & 7;
#pragma unroll
            for (int t = 0; t < 12; ++t) {
                const int kl = t * 16 + lr;
                const int nk = (kl < i * 64) ? kl : kl + 64;
                const int dk = nk >> 6, hk = (nk >> 3) & 7, wk = nk & 7;
                relb[t][r] = (i - dk + 3) * 225 + (hq - hk + 7) * 15 + (wq_ - wk + 7);
            }
        }
    }

    for (int h = 0; h < 8; ++h) {
        // ---- stage q_h: 64 rows x 32 cols (1 float4 per thread)
        {
            const int row = tid >> 2, g = tid & 3;
            *reinterpret_cast<float4*>(&qh[row][g * 8]) =
                *reinterpret_cast<const float4*>(&qo[qbase + (size_t)row * C_ + h * 32 + g * 8]);
        }
        // ---- stage k_h rows + v_h transposed
#pragma unroll
        for (int t = 0; t < 3; ++t) {
            const int c = tid + t * 256;
            const int kl = c >> 2, g = c & 3;
            const int nk = (kl < i * 64) ? kl : kl + 64;
            const size_t base = ((size_t)(wb * 256 + nk)) * C_ + h * 32 + g * 8;
            *reinterpret_cast<float4*>(&kt[kl][g * 8]) =
                *reinterpret_cast<const float4*>(&kb[base]);
            u16x8 vv = *reinterpret_cast<const u16x8*>(&vb[base]);
#pragma unroll
            for (int j = 0; j < 8; ++j) vtt[g * 8 + j][kl] = vv[j];
        }
        // ---- stage bias column for head h
        for (int j = tid; j < RPB_N; j += 256) biasld[j] = rpbp[j * 8 + h];
        __syncthreads();

        // ---- QK^T: 12 MFMAs, K=32 in one shot
        floatx4 acc[12];
#pragma unroll
        for (int t = 0; t < 12; ++t) acc[t] = (floatx4){0.f, 0.f, 0.f, 0.f};
        {
            const bf16x8 af = *reinterpret_cast<const bf16x8*>(&qh[wave * 16 + lr][lq * 8]);
#pragma unroll
            for (int t = 0; t < 12; ++t) {
                const bf16x8 bfv = *reinterpret_cast<const bf16x8*>(&kt[t * 16 + lr][lq * 8]);
                acc[t] = __builtin_amdgcn_mfma_f32_16x16x32_bf16(af, bfv, acc[t], 0, 0, 0);
            }
        }

        // ---- scale + bias (in-register), row max
        float mrow[4] = {-1e30f, -1e30f, -1e30f, -1e30f};
#pragma unroll
        for (int t = 0; t < 12; ++t)
#pragma unroll
            for (int r = 0; r < 4; ++r) {
                const float v = fmaf(acc[t][r], QSCALE, biasld[relb[t][r]]);
                acc[t][r] = v;
                mrow[r] = fmaxf(mrow[r], v);
            }
#pragma unroll
        for (int off = 8; off >= 1; off >>= 1)
#pragma unroll
            for (int r = 0; r < 4; ++r)
                mrow[r] = fmaxf(mrow[r], __shfl_xor(mrow[r], off, 64));

        // ---- exp + row sum
        float srow[4] = {0.f, 0.f, 0.f, 0.f};
#pragma unroll
        for (int t = 0; t < 12; ++t)
#pragma unroll
            for (int r = 0; r < 4; ++r) {
                const float e = __expf(acc[t][r] - mrow[r]);
                acc[t][r] = e;
                srow[r] += e;
            }
#pragma unroll
        for (int off = 8; off >= 1; off >>= 1)
#pragma unroll
            for (int r = 0; r < 4; ++r)
                srow[r] += __shfl_xor(srow[r], off, 64);
#pragma unroll
        for (int r = 0; r < 4; ++r) srow[r] = 1.0f / srow[r];

        // ---- P -> LDS (bf16): row = 16w + lq*4 + r, col = t*16 + lr
#pragma unroll
        for (int t = 0; t < 12; ++t)
#pragma unroll
            for (int r = 0; r < 4; ++r)
                sp[wave * 16 + lq * 4 + r][t * 16 + lr] = f2bf(acc[t][r] * srow[r]);
        __syncthreads();

        // ---- PV: O[16x32] per wave = P[16x192] @ V[192x32], 12 MFMAs
        floatx4 oacc[2];
        oacc[0] = (floatx4){0.f, 0.f, 0.f, 0.f};
        oacc[1] = (floatx4){0.f, 0.f, 0.f, 0.f};
#pragma unroll
        for (int kc = 0; kc < 6; ++kc) {
            const bf16x8 pa = *reinterpret_cast<const bf16x8*>(&sp[wave * 16 + lr][kc * 32 + lq * 8]);
#pragma unroll
            for (int nt = 0; nt < 2; ++nt) {
                const bf16x8 bv = *reinterpret_cast<const bf16x8*>(&vtt[nt * 16 + lr][kc * 32 + lq * 8]);
                oacc[nt] = __builtin_amdgcn_mfma_f32_16x16x32_bf16(pa, bv, oacc[nt], 0, 0, 0);
            }
        }
        // ---- write O over q columns for head h
#pragma unroll
        for (int nt = 0; nt < 2; ++nt)
#pragma unroll
            for (int r = 0; r < 4; ++r)
                qo[qbase + (size_t)(wave * 16 + lq * 4 + r) * C_ + h * 32 + nt * 16 + lr] =
                    f2bf(oacc[nt][r]);
        __syncthreads();   // protect LDS restage next head
    }
}

// ----------------------------------------------------------------- launch
extern "C" void kernel_launch(void* const* d_in, const int* in_sizes, int n_in,
                              void* d_out, int out_size, void* d_ws, size_t ws_size,
                              hipStream_t stream) {
    const float* x    = (const float*)d_in[0];
    const float* ln1g = (const float*)d_in[1];
    const float* ln1b = (const float*)d_in[2];
    const float* ln2g = (const float*)d_in[3];
    const float* ln2b = (const float*)d_in[4];
    const float* wq   = (const float*)d_in[5];
    const float* wkv  = (const float*)d_in[6];
    const float* wp   = (const float*)d_in[7];
    const float* bp   = (const float*)d_in[8];
    const float* rpb  = (const float*)d_in[9];
    const float* w1   = (const float*)d_in[10];
    const float* b1   = (const float*)d_in[11];
    const float* w2   = (const float*)d_in[12];
    const float* b2   = (const float*)d_in[13];
    float* outf = (float*)d_out;
    u16*   outu = (u16*)d_out;          // bf16 scratch view: [k | v]
    u16*   ws16 = (u16*)d_ws;

    u16* r0 = ws16;                     // xw -> q -> o -> oproj -> h1 -> h2
    u16* r1 = ws16 + R1_ELEMS;          // xn
    u16* kbuf = outu;
    u16* vbuf = outu + R1_ELEMS;

    // 1. LN1 + window partition (fp32 -> bf16)
    ln_part_kernel<<<NTOK / 4, 256, 0, stream>>>(x, ln1g, ln1b, r0);

    // 2. k, v = xw @ wkv halves -> d_out bf16 halves
    gemm256_kernel<<<NTOK / 128, 256, 0, stream>>>(r0, wkv, 512, 0,   kbuf, nullptr, nullptr, 0);
    gemm256_kernel<<<NTOK / 128, 256, 0, stream>>>(r0, wkv, 512, 256, vbuf, nullptr, nullptr, 0);
    // 3. q = xw @ wq -> r0 (in-place)
    gemm256_kernel<<<NTOK / 128, 256, 0, stream>>>(r0, wq, 256, 0, r0, nullptr, nullptr, 0);

    // 4. attention: o overwrites q in r0
    attn_kernel<<<512 * 4, 256, 0, stream>>>(r0, kbuf, vbuf, rpb);

    // 5. oproj = o @ wp + bp -> r0 (in-place)
    gemm256_kernel<<<NTOK / 128, 256, 0, stream>>>(r0, wp, 256, 0, r0, nullptr, bp, 1);

    // 6. y = x + reverse(oproj) -> d_out fp32 (k,v dead); xn = LN2(y) -> r1
    resid_ln2_kernel<<<NTOK / 4, 256, 0, stream>>>(x, r0, ln2g, ln2b, outf, r1);

    // 7. MLP, hid split in two 256-halves, fp32 accumulation into d_out
    gemm256_kernel<<<NTOK / 128, 256, 0, stream>>>(r1, w1, 512, 0,   r0, nullptr, b1, 2);        // h1
    gemm256_kernel<<<NTOK / 128, 256, 0, stream>>>(r0, w2, 256, 0,   nullptr, outf, b2, 5);      // out = y + b2 + h1@w2a
    gemm256_kernel<<<NTOK / 128, 256, 0, stream>>>(r1, w1, 512, 256, r0, nullptr, b1 + 256, 2);  // h2
    gemm256_kernel<<<NTOK / 128, 256, 0, stream>>>(r0, w2 + 65536, 256, 0, nullptr, outf, nullptr, 6); // out += h2@w2b
}

// Round 2
// 1882.191 us; speedup vs baseline: 1.9168x; 1.2632x over previous
//
#include <hip/hip_runtime.h>

typedef unsigned short u16;
typedef __bf16 bf16x8 __attribute__((ext_vector_type(8)));
typedef float floatx4 __attribute__((ext_vector_type(4)));
typedef unsigned short u16x8 __attribute__((ext_vector_type(8)));

#define C_  256
#define NTOK 131072                  // B*D*H*W = 8*4*64*64
#define QSCALE 0.17677669529663687f  // 1/sqrt(32)
#define RPB_N 1575                   // (2*4-1)*(2*8-1)*(2*8-1)

// ws: two bf16 regions of NTOK*256 elems (+1 MB weights if ws_size allows).
// r0: xw -> q (in-place) -> o (in-place) -> oproj (in-place) -> h1
// r1: xn -> h2 (in-place)   [tight-ws: also phase-A weights before xn exists]
// d_out: [k | v] bf16 halves during attention, then y fp32 (RMW'd into out).
#define R1_ELEMS 33554432ull

__device__ __forceinline__ float bf2f(u16 u) {
    return __uint_as_float(((unsigned)u) << 16);
}
__device__ __forceinline__ u16 f2bf(float f) {
    unsigned u = __float_as_uint(f);
    return (u16)((u + 0x7FFFu + ((u >> 16) & 1u)) >> 16);  // RNE
}

// ------------------------------------------------- weight convert fp32->bf16 B^T
// W fp32 [Kd][N] row-major -> out bf16 [N][Kd], Kd = 1<<ks. out[n*Kd+k] = W[k*N+n].
__global__ __launch_bounds__(256) void wcvt_kernel(
    const float* __restrict__ W, int N, int ks, u16* __restrict__ out)
{
    const int idx = blockIdx.x * 256 + threadIdx.x;
    const int n = idx >> ks;
    const int k = idx & ((1 << ks) - 1);
    out[idx] = f2bf(W[(size_t)k * N + n]);
}

// ---------------------------------------------------------- LN1 + partition
__global__ __launch_bounds__(256) void ln_part_kernel(
    const float* __restrict__ x, const float* __restrict__ g, const float* __restrict__ bb,
    u16* __restrict__ xw)
{
    const int lane = threadIdx.x & 63;
    const int wave = threadIdx.x >> 6;
    const int t = blockIdx.x * 4 + wave;          // window row: wb*256+n
    const int wb = t >> 8, n = t & 255;
    const int bidx = wb >> 6, hb = (wb >> 3) & 7, wbl = wb & 7;
    const int d = n >> 6, hh = (n >> 3) & 7, ww = n & 7;
    const size_t src = ((((size_t)bidx * 4 + d) * 64 + hb * 8 + hh) * 64 + wbl * 8 + ww) * C_;
    const int c0 = lane * 4;
    float4 raw = *reinterpret_cast<const float4*>(&x[src + c0]);
    float v0 = raw.x, v1 = raw.y, v2 = raw.z, v3 = raw.w;
    float s = v0 + v1 + v2 + v3;
    float sq = v0 * v0 + v1 * v1 + v2 * v2 + v3 * v3;
#pragma unroll
    for (int off = 32; off > 0; off >>= 1) {
        s  += __shfl_xor(s, off, 64);
        sq += __shfl_xor(sq, off, 64);
    }
    const float mean = s * (1.0f / 256.0f);
    const float var  = sq * (1.0f / 256.0f) - mean * mean;
    const float rstd = rsqrtf(var + 1e-5f);
    float4 gr = *reinterpret_cast<const float4*>(&g[c0]);
    float4 br = *reinterpret_cast<const float4*>(&bb[c0]);
    ushort4 outv;
    outv.x = f2bf((v0 - mean) * rstd * gr.x + br.x);
    outv.y = f2bf((v1 - mean) * rstd * gr.y + br.y);
    outv.z = f2bf((v2 - mean) * rstd * gr.z + br.z);
    outv.w = f2bf((v3 - mean) * rstd * gr.w + br.w);
    *reinterpret_cast<ushort4*>(&xw[(size_t)t * C_ + c0]) = outv;
}

// ------------------------------------------------- residual + LN2
__global__ __launch_bounds__(256) void resid_ln2_kernel(
    const float* __restrict__ x, const u16* __restrict__ oproj,
    const float* __restrict__ g, const float* __restrict__ bb,
    float* __restrict__ y, u16* __restrict__ xn)
{
    const int lane = threadIdx.x & 63;
    const int wave = threadIdx.x >> 6;
    const int t = blockIdx.x * 4 + wave;          // x-layout token
    const int wpos = t & 63;
    const int h = (t >> 6) & 63;
    const int d = (t >> 12) & 3;
    const int bidx = t >> 14;
    const int wr = (((bidx * 8) + (h >> 3)) * 8 + (wpos >> 3)) * 256
                 + d * 64 + (h & 7) * 8 + (wpos & 7);   // window row
    const int c0 = lane * 4;
    float4 xr = *reinterpret_cast<const float4*>(&x[(size_t)t * C_ + c0]);
    ushort4 pr = *reinterpret_cast<const ushort4*>(&oproj[(size_t)wr * C_ + c0]);
    float v0 = xr.x + bf2f(pr.x);
    float v1 = xr.y + bf2f(pr.y);
    float v2 = xr.z + bf2f(pr.z);
    float v3 = xr.w + bf2f(pr.w);
    float s = v0 + v1 + v2 + v3;
    float sq = v0 * v0 + v1 * v1 + v2 * v2 + v3 * v3;
#pragma unroll
    for (int off = 32; off > 0; off >>= 1) {
        s  += __shfl_xor(s, off, 64);
        sq += __shfl_xor(sq, off, 64);
    }
    const float mean = s * (1.0f / 256.0f);
    const float var  = sq * (1.0f / 256.0f) - mean * mean;
    const float rstd = rsqrtf(var + 1e-5f);
    float4 yv; yv.x = v0; yv.y = v1; yv.z = v2; yv.w = v3;
    *reinterpret_cast<float4*>(&y[(size_t)t * C_ + c0]) = yv;
    float4 gr = *reinterpret_cast<const float4*>(&g[c0]);
    float4 br = *reinterpret_cast<const float4*>(&bb[c0]);
    ushort4 nv;
    nv.x = f2bf((v0 - mean) * rstd * gr.x + br.x);
    nv.y = f2bf((v1 - mean) * rstd * gr.y + br.y);
    nv.z = f2bf((v2 - mean) * rstd * gr.z + br.z);
    nv.w = f2bf((v3 - mean) * rstd * gr.w + br.w);
    *reinterpret_cast<ushort4*>(&xn[(size_t)t * C_ + c0]) = nv;
}

// ----------------------------------------------------------- MFMA bf16 GEMM
// M=NTOK, N=256, K=kdim (256 or 512). One block per 128-row strip (full N).
// A: bf16 [M x 256] (k<256); A2: second buffer for k in [256,512).
// B: either Bt bf16 B^T [nc0+n][kdim] (fast), or Bgf fp32 natural [kdim x ldb]
//    column window [nc0,nc0+256) converted in-LDS (legacy fallback).
// mode: 0 plain->Cm(bf16), 1 +bias->Cm, 2 +bias+GELU->Cm, 5 Cf = Cf + acc + bias.
// In-place safe (Cm/Cf aliasing A/A2): blocks read only their own 128-row
// strip (all reads before epilogue) and write only that strip.
__global__ __launch_bounds__(256) void gemm256_kernel(
    const u16* __restrict__ A, const u16* __restrict__ A2,
    const u16* __restrict__ Bt, const float* __restrict__ Bgf, int ldb, int nc0,
    int kdim,
    u16* __restrict__ Cm, float* __restrict__ Cf, const float* __restrict__ bias,
    int mode)
{
    __shared__ __align__(16) u16 As[128][40];   // [row][k], padded
    __shared__ __align__(16) u16 Bs[256][40];   // [n][k],  padded (B^T tile)
    const int tid  = threadIdx.x;
    const int lane = tid & 63, wave = tid >> 6;
    const int lr = lane & 15, lq = lane >> 4;
    const int row0 = blockIdx.x * 128;
    const int wm = (wave & 1) * 64;      // m offset within tile
    const int wn = (wave >> 1) * 128;    // n offset within tile
    const bool fastB = (Bt != nullptr);

    floatx4 acc[4][8] = {};
    float4 apf[2], bpf[4];

    // initial prefetch (k0 = 0)
#pragma unroll
    for (int t = 0; t < 2; ++t) {
        int c = tid + t * 256;
        int r = c >> 2, cc = c & 3;
        apf[t] = *reinterpret_cast<const float4*>(&A[(size_t)(row0 + r) * 256 + cc * 8]);
    }
    if (fastB) {
#pragma unroll
        for (int t = 0; t < 4; ++t) {
            int c = tid + t * 256;
            int r = c >> 2, g = c & 3;
            bpf[t] = *reinterpret_cast<const float4*>(&Bt[(size_t)(nc0 + r) * kdim + g * 8]);
        }
    }

    for (int k0 = 0; k0 < kdim; k0 += 32) {
        // ---- write staged registers to LDS
#pragma unroll
        for (int t = 0; t < 2; ++t) {
            int c = tid + t * 256;
            int r = c >> 2, cc = c & 3;
            *reinterpret_cast<float4*>(&As[r][cc * 8]) = apf[t];
        }
        if (fastB) {
#pragma unroll
            for (int t = 0; t < 4; ++t) {
                int c = tid + t * 256;
                int r = c >> 2, g = c & 3;
                *reinterpret_cast<float4*>(&Bs[r][g * 8]) = bpf[t];
            }
        } else {
            // legacy: fp32 -> bf16 with in-LDS transpose (tight-ws fallback only)
#pragma unroll
            for (int t = 0; t < 8; ++t) {
                int c = tid + t * 256;
                int kk = c >> 6, ng = c & 63;
                float4 bv = *reinterpret_cast<const float4*>(
                    &Bgf[(size_t)(k0 + kk) * ldb + nc0 + ng * 4]);
                Bs[ng * 4 + 0][kk] = f2bf(bv.x);
                Bs[ng * 4 + 1][kk] = f2bf(bv.y);
                Bs[ng * 4 + 2][kk] = f2bf(bv.z);
                Bs[ng * 4 + 3][kk] = f2bf(bv.w);
            }
        }
        // ---- issue next-iter global prefetch (flies during MFMA phase)
        const int kn = k0 + 32;
        if (kn < kdim) {
            const u16* Asrc = (kn < 256) ? A : A2;
            const int ka = kn & 255;
#pragma unroll
            for (int t = 0; t < 2; ++t) {
                int c = tid + t * 256;
                int r = c >> 2, cc = c & 3;
                apf[t] = *reinterpret_cast<const float4*>(
                    &Asrc[(size_t)(row0 + r) * 256 + ka + cc * 8]);
            }
            if (fastB) {
#pragma unroll
                for (int t = 0; t < 4; ++t) {
                    int c = tid + t * 256;
                    int r = c >> 2, g = c & 3;
                    bpf[t] = *reinterpret_cast<const float4*>(
                        &Bt[(size_t)(nc0 + r) * kdim + kn + g * 8]);
                }
            }
        }
        __syncthreads();
        bf16x8 af[4], bfv[8];
#pragma unroll
        for (int mt = 0; mt < 4; ++mt)
            af[mt] = *reinterpret_cast<const bf16x8*>(&As[wm + mt * 16 + lr][lq * 8]);
#pragma unroll
        for (int nt = 0; nt < 8; ++nt)
            bfv[nt] = *reinterpret_cast<const bf16x8*>(&Bs[wn + nt * 16 + lr][lq * 8]);
#pragma unroll
        for (int mt = 0; mt < 4; ++mt)
#pragma unroll
            for (int nt = 0; nt < 8; ++nt)
                acc[mt][nt] = __builtin_amdgcn_mfma_f32_16x16x32_bf16(
                    af[mt], bfv[nt], acc[mt][nt], 0, 0, 0);
        __syncthreads();
    }

#pragma unroll
    for (int mt = 0; mt < 4; ++mt) {
#pragma unroll
        for (int nt = 0; nt < 8; ++nt) {
#pragma unroll
            for (int r = 0; r < 4; ++r) {
                int row = row0 + wm + mt * 16 + lq * 4 + r;
                int col = wn + nt * 16 + lr;
                size_t idx = (size_t)row * 256 + col;
                float v = acc[mt][nt][r];
                if (mode != 0) v += bias[col];
                if (mode == 2) v = 0.5f * v * (1.0f + erff(v * 0.70710678118654752f));
                if (mode == 5) {
                    v += Cf[idx];          // fp32 accumulate in place (own element)
                    Cf[idx] = v;
                } else {
                    Cm[idx] = f2bf(v);
                }
            }
        }
    }
}

// -------------------------------------------------------------- attention
// MFMA version. block = (window wb, depth-slice i); 8 heads sequential.
// 64 q x 192 keys, hd=32. 4 waves: wave w owns q-rows [16w, 16w+16).
__global__ __launch_bounds__(256) void attn_kernel(
    u16* __restrict__ qo, const u16* __restrict__ kb, const u16* __restrict__ vb,
    const float* __restrict__ rpbp)
{
    __shared__ __align__(16) u16 qh[64][40];     // [q][c]
    __shared__ __align__(16) u16 kt[192][40];    // [key][c]
    __shared__ __align__(16) u16 vtt[32][200];   // [d][key]  (V^T)
    __shared__ __align__(16) u16 sp[64][200];    // [q][key]  (P, bf16)
    __shared__ float biasld[RPB_N + 1];          // rpb column for head h

    const int wb = blockIdx.x >> 2;
    const int i  = blockIdx.x & 3;
    const int tid = threadIdx.x;
    const int lane = tid & 63, wave = tid >> 6;
    const int lr = lane & 15, lq = lane >> 4;
    const size_t qbase = ((size_t)(wb * 256 + i * 64)) * C_;

    int relb[12][4];
    {
        const int q0 = wave * 16 + lq * 4;
#pragma unroll
        for (int r = 0; r < 4; ++r) {
            const int q = q0 + r;
            const int hq = q >> 3, wq_ = q & 7;
#pragma unroll
            for (int t = 0; t < 12; ++t) {
                const int kl = t * 16 + lr;
                const int nk = (kl < i * 64) ? kl : kl + 64;
                const int dk = nk >> 6, hk = (nk >> 3) & 7, wk = nk & 7;
                relb[t][r] = (i - dk + 3) * 225 + (hq - hk + 7) * 15 + (wq_ - wk + 7);
            }
        }
    }

    for (int h = 0; h < 8; ++h) {
        {
            const int row = tid >> 2, g = tid & 3;
            *reinterpret_cast<float4*>(&qh[row][g * 8]) =
                *reinterpret_cast<const float4*>(&qo[qbase + (size_t)row * C_ + h * 32 + g * 8]);
        }
#pragma unroll
        for (int t = 0; t < 3; ++t) {
            const int c = tid + t * 256;
            const int kl = c >> 2, g = c & 3;
            const int nk = (kl < i * 64) ? kl : kl + 64;
            const size_t base = ((size_t)(wb * 256 + nk)) * C_ + h * 32 + g * 8;
            *reinterpret_cast<float4*>(&kt[kl][g * 8]) =
                *reinterpret_cast<const float4*>(&kb[base]);
            u16x8 vv = *reinterpret_cast<const u16x8*>(&vb[base]);
#pragma unroll
            for (int j = 0; j < 8; ++j) vtt[g * 8 + j][kl] = vv[j];
        }
        for (int j = tid; j < RPB_N; j += 256) biasld[j] = rpbp[j * 8 + h];
        __syncthreads();

        floatx4 acc[12];
#pragma unroll
        for (int t = 0; t < 12; ++t) acc[t] = (floatx4){0.f, 0.f, 0.f, 0.f};
        {
            const bf16x8 af = *reinterpret_cast<const bf16x8*>(&qh[wave * 16 + lr][lq * 8]);
#pragma unroll
            for (int t = 0; t < 12; ++t) {
                const bf16x8 bfv = *reinterpret_cast<const bf16x8*>(&kt[t * 16 + lr][lq * 8]);
                acc[t] = __builtin_amdgcn_mfma_f32_16x16x32_bf16(af, bfv, acc[t], 0, 0, 0);
            }
        }

        float mrow[4] = {-1e30f, -1e30f, -1e30f, -1e30f};
#pragma unroll
        for (int t = 0; t < 12; ++t)
#pragma unroll
            for (int r = 0; r < 4; ++r) {
                const float v = fmaf(acc[t][r], QSCALE, biasld[relb[t][r]]);
                acc[t][r] = v;
                mrow[r] = fmaxf(mrow[r], v);
            }
#pragma unroll
        for (int off = 8; off >= 1; off >>= 1)
#pragma unroll
            for (int r = 0; r < 4; ++r)
                mrow[r] = fmaxf(mrow[r], __shfl_xor(mrow[r], off, 64));

        float srow[4] = {0.f, 0.f, 0.f, 0.f};
#pragma unroll
        for (int t = 0; t < 12; ++t)
#pragma unroll
            for (int r = 0; r < 4; ++r) {
                const float e = __expf(acc[t][r] - mrow[r]);
                acc[t][r] = e;
                srow[r] += e;
            }
#pragma unroll
        for (int off = 8; off >= 1; off >>= 1)
#pragma unroll
            for (int r = 0; r < 4; ++r)
                srow[r] += __shfl_xor(srow[r], off, 64);
#pragma unroll
        for (int r = 0; r < 4; ++r) srow[r] = 1.0f / srow[r];

#pragma unroll
        for (int t = 0; t < 12; ++t)
#pragma unroll
            for (int r = 0; r < 4; ++r)
                sp[wave * 16 + lq * 4 + r][t * 16 + lr] = f2bf(acc[t][r] * srow[r]);
        __syncthreads();

        floatx4 oacc[2];
        oacc[0] = (floatx4){0.f, 0.f, 0.f, 0.f};
        oacc[1] = (floatx4){0.f, 0.f, 0.f, 0.f};
#pragma unroll
        for (int kc = 0; kc < 6; ++kc) {
            const bf16x8 pa = *reinterpret_cast<const bf16x8*>(&sp[wave * 16 + lr][kc * 32 + lq * 8]);
#pragma unroll
            for (int nt = 0; nt < 2; ++nt) {
                const bf16x8 bv = *reinterpret_cast<const bf16x8*>(&vtt[nt * 16 + lr][kc * 32 + lq * 8]);
                oacc[nt] = __builtin_amdgcn_mfma_f32_16x16x32_bf16(pa, bv, oacc[nt], 0, 0, 0);
            }
        }
#pragma unroll
        for (int nt = 0; nt < 2; ++nt)
#pragma unroll
            for (int r = 0; r < 4; ++r)
                qo[qbase + (size_t)(wave * 16 + lq * 4 + r) * C_ + h * 32 + nt * 16 + lr] =
                    f2bf(oacc[nt][r]);
        __syncthreads();   // protect LDS restage next head
    }
}

// ----------------------------------------------------------------- launch
extern "C" void kernel_launch(void* const* d_in, const int* in_sizes, int n_in,
                              void* d_out, int out_size, void* d_ws, size_t ws_size,
                              hipStream_t stream) {
    const float* x    = (const float*)d_in[0];
    const float* ln1g = (const float*)d_in[1];
    const float* ln1b = (const float*)d_in[2];
    const float* ln2g = (const float*)d_in[3];
    const float* ln2b = (const float*)d_in[4];
    const float* wq   = (const float*)d_in[5];
    const float* wkv  = (const float*)d_in[6];
    const float* wp   = (const float*)d_in[7];
    const float* bp   = (const float*)d_in[8];
    const float* rpb  = (const float*)d_in[9];
    const float* w1   = (const float*)d_in[10];
    const float* b1   = (const float*)d_in[11];
    const float* w2   = (const float*)d_in[12];
    const float* b2   = (const float*)d_in[13];
    float* outf = (float*)d_out;
    u16*   outu = (u16*)d_out;          // bf16 scratch view: [k | v]
    u16*   ws16 = (u16*)d_ws;

    u16* r0 = ws16;                     // xw -> q -> o -> oproj -> h1
    u16* r1 = ws16 + R1_ELEMS;          // xn -> h2 (in-place)
    u16* kbuf = outu;
    u16* vbuf = outu + R1_ELEMS;

    // Weight placement: fast if ws has 2 regions + 1 MB slack; else phase-A
    // weights live in r1 (dead before xn is written) and w1/w2 use legacy path.
    const bool big = ws_size >= (134217728ull + 1048576ull + 65536ull);
    u16* wbuf = big ? (ws16 + 2 * R1_ELEMS) : r1;
    u16* wqT  = wbuf;                   // [256][256]
    u16* wkvT = wbuf + 65536;           // [512][256]
    u16* wpT  = wbuf + 196608;          // [256][256]
    u16* w1T  = big ? (wbuf + 262144) : nullptr;   // [512][256]
    u16* w2T  = big ? (wbuf + 393216) : nullptr;   // [256][512]

    // 0. convert weights to bf16 B^T (once)
    wcvt_kernel<<<256, 256, 0, stream>>>(wq,  256, 8, wqT);
    wcvt_kernel<<<512, 256, 0, stream>>>(wkv, 512, 8, wkvT);
    wcvt_kernel<<<256, 256, 0, stream>>>(wp,  256, 8, wpT);
    if (big) {
        wcvt_kernel<<<512, 256, 0, stream>>>(w1, 512, 8, w1T);
        wcvt_kernel<<<512, 256, 0, stream>>>(w2, 256, 9, w2T);
    }

    // 1. LN1 + window partition (fp32 -> bf16)
    ln_part_kernel<<<NTOK / 4, 256, 0, stream>>>(x, ln1g, ln1b, r0);

    // 2. k, v = xw @ wkv halves -> d_out bf16 halves
    gemm256_kernel<<<NTOK / 128, 256, 0, stream>>>(r0, r0, wkvT, wkv, 512, 0,   256, kbuf, nullptr, nullptr, 0);
    gemm256_kernel<<<NTOK / 128, 256, 0, stream>>>(r0, r0, wkvT, wkv, 512, 256, 256, vbuf, nullptr, nullptr, 0);
    // 3. q = xw @ wq -> r0 (in-place)
    gemm256_kernel<<<NTOK / 128, 256, 0, stream>>>(r0, r0, wqT, wq, 256, 0, 256, r0, nullptr, nullptr, 0);

    // 4. attention: o overwrites q in r0
    attn_kernel<<<512 * 4, 256, 0, stream>>>(r0, kbuf, vbuf, rpb);

    // 5. oproj = o @ wp + bp -> r0 (in-place)
    gemm256_kernel<<<NTOK / 128, 256, 0, stream>>>(r0, r0, wpT, wp, 256, 0, 256, r0, nullptr, bp, 1);

    // 6. y = x + reverse(oproj) -> d_out fp32 (k,v dead); xn = LN2(y) -> r1
    //    (tight-ws: this overwrites phase-A weights in r1 — they are dead now)
    resid_ln2_kernel<<<NTOK / 4, 256, 0, stream>>>(x, r0, ln2g, ln2b, outf, r1);

    // 7. MLP: h1 -> r0 (oproj dead), h2 -> r1 in-place over xn,
    //    then single K=512 GEMM: out = y + [h1|h2] @ w2^T + b2 (fp32 RMW once)
    gemm256_kernel<<<NTOK / 128, 256, 0, stream>>>(r1, r1, w1T, w1, 512, 0,   256, r0, nullptr, b1,       2);
    gemm256_kernel<<<NTOK / 128, 256, 0, stream>>>(r1, r1, w1T, w1, 512, 256, 256, r1, nullptr, b1 + 256, 2);
    gemm256_kernel<<<NTOK / 128, 256, 0, stream>>>(r0, r1, w2T, w2, 256, 0,   512, nullptr, outf, b2,     5);
}

// Round 3
// 961.085 us; speedup vs baseline: 3.7539x; 1.9584x over previous
//
#include <hip/hip_runtime.h>

typedef unsigned short u16;
typedef __bf16 bf16x8 __attribute__((ext_vector_type(8)));
typedef float floatx4 __attribute__((ext_vector_type(4)));
typedef unsigned short u16x8 __attribute__((ext_vector_type(8)));

#define C_  256
#define NTOK 131072                  // B*D*H*W = 8*4*64*64
#define QSCALE 0.17677669529663687f  // 1/sqrt(32)
#define RPB_N 1575                   // (2*4-1)*(2*8-1)*(2*8-1)

// ws: two bf16 regions of NTOK*256 elems.
// r0: xw -> q (in-place) -> o (in-place) -> oproj (in-place) -> h1
// r1: xn -> h2 (in-place)
// d_out: [k | v] bf16 halves during attention, then y fp32 (RMW'd into out).
#define R1_ELEMS 33554432ull

// All weights, pre-converted to bf16 B^T, in a static device buffer (1 MB).
// offsets (u16 elems): wq 0, wkv 65536, wp 196608, w1 262144, w2 393216
__device__ u16 g_wT[524288];

__device__ __forceinline__ float bf2f(u16 u) {
    return __uint_as_float(((unsigned)u) << 16);
}
__device__ __forceinline__ u16 f2bf(float f) {
    unsigned u = __float_as_uint(f);
    return (u16)((u + 0x7FFFu + ((u >> 16) & 1u)) >> 16);  // RNE
}

// async global->LDS, 16B per lane. LDS dest is wave-uniform base + lane*16;
// our LDS layouts are lane-linear so dest == base + lane*16 by construction.
#define GL16(gsrc, ldst) __builtin_amdgcn_global_load_lds(                    \
    (const __attribute__((address_space(1))) void*)(gsrc),                    \
    (__attribute__((address_space(3))) void*)(ldst), 16, 0, 0)

// ------------------------------------------------- weight convert fp32->bf16 B^T
// W fp32 [Kd][N] row-major -> g_wT[ofs + n*Kd + k], Kd = 1<<ks.
__global__ __launch_bounds__(256) void wcvt_kernel(
    const float* __restrict__ W, int N, int ks, int ofs)
{
    const int idx = blockIdx.x * 256 + threadIdx.x;
    const int n = idx >> ks;
    const int k = idx & ((1 << ks) - 1);
    g_wT[ofs + idx] = f2bf(W[(size_t)k * N + n]);
}

// ---------------------------------------------------------- LN1 + partition
__global__ __launch_bounds__(256) void ln_part_kernel(
    const float* __restrict__ x, const float* __restrict__ g, const float* __restrict__ bb,
    u16* __restrict__ xw)
{
    const int lane = threadIdx.x & 63;
    const int wave = threadIdx.x >> 6;
    const int t = blockIdx.x * 4 + wave;          // window row: wb*256+n
    const int wb = t >> 8, n = t & 255;
    const int bidx = wb >> 6, hb = (wb >> 3) & 7, wbl = wb & 7;
    const int d = n >> 6, hh = (n >> 3) & 7, ww = n & 7;
    const size_t src = ((((size_t)bidx * 4 + d) * 64 + hb * 8 + hh) * 64 + wbl * 8 + ww) * C_;
    const int c0 = lane * 4;
    float4 raw = *reinterpret_cast<const float4*>(&x[src + c0]);
    float v0 = raw.x, v1 = raw.y, v2 = raw.z, v3 = raw.w;
    float s = v0 + v1 + v2 + v3;
    float sq = v0 * v0 + v1 * v1 + v2 * v2 + v3 * v3;
#pragma unroll
    for (int off = 32; off > 0; off >>= 1) {
        s  += __shfl_xor(s, off, 64);
        sq += __shfl_xor(sq, off, 64);
    }
    const float mean = s * (1.0f / 256.0f);
    const float var  = sq * (1.0f / 256.0f) - mean * mean;
    const float rstd = rsqrtf(var + 1e-5f);
    float4 gr = *reinterpret_cast<const float4*>(&g[c0]);
    float4 br = *reinterpret_cast<const float4*>(&bb[c0]);
    ushort4 outv;
    outv.x = f2bf((v0 - mean) * rstd * gr.x + br.x);
    outv.y = f2bf((v1 - mean) * rstd * gr.y + br.y);
    outv.z = f2bf((v2 - mean) * rstd * gr.z + br.z);
    outv.w = f2bf((v3 - mean) * rstd * gr.w + br.w);
    *reinterpret_cast<ushort4*>(&xw[(size_t)t * C_ + c0]) = outv;
}

// ------------------------------------------------- residual + LN2
__global__ __launch_bounds__(256) void resid_ln2_kernel(
    const float* __restrict__ x, const u16* __restrict__ oproj,
    const float* __restrict__ g, const float* __restrict__ bb,
    float* __restrict__ y, u16* __restrict__ xn)
{
    const int lane = threadIdx.x & 63;
    const int wave = threadIdx.x >> 6;
    const int t = blockIdx.x * 4 + wave;          // x-layout token
    const int wpos = t & 63;
    const int h = (t >> 6) & 63;
    const int d = (t >> 12) & 3;
    const int bidx = t >> 14;
    const int wr = (((bidx * 8) + (h >> 3)) * 8 + (wpos >> 3)) * 256
                 + d * 64 + (h & 7) * 8 + (wpos & 7);   // window row
    const int c0 = lane * 4;
    float4 xr = *reinterpret_cast<const float4*>(&x[(size_t)t * C_ + c0]);
    ushort4 pr = *reinterpret_cast<const ushort4*>(&oproj[(size_t)wr * C_ + c0]);
    float v0 = xr.x + bf2f(pr.x);
    float v1 = xr.y + bf2f(pr.y);
    float v2 = xr.z + bf2f(pr.z);
    float v3 = xr.w + bf2f(pr.w);
    float s = v0 + v1 + v2 + v3;
    float sq = v0 * v0 + v1 * v1 + v2 * v2 + v3 * v3;
#pragma unroll
    for (int off = 32; off > 0; off >>= 1) {
        s  += __shfl_xor(s, off, 64);
        sq += __shfl_xor(sq, off, 64);
    }
    const float mean = s * (1.0f / 256.0f);
    const float var  = sq * (1.0f / 256.0f) - mean * mean;
    const float rstd = rsqrtf(var + 1e-5f);
    float4 yv; yv.x = v0; yv.y = v1; yv.z = v2; yv.w = v3;
    *reinterpret_cast<float4*>(&y[(size_t)t * C_ + c0]) = yv;
    float4 gr = *reinterpret_cast<const float4*>(&g[c0]);
    float4 br = *reinterpret_cast<const float4*>(&bb[c0]);
    ushort4 nv;
    nv.x = f2bf((v0 - mean) * rstd * gr.x + br.x);
    nv.y = f2bf((v1 - mean) * rstd * gr.y + br.y);
    nv.z = f2bf((v2 - mean) * rstd * gr.z + br.z);
    nv.w = f2bf((v3 - mean) * rstd * gr.w + br.w);
    *reinterpret_cast<ushort4*>(&xn[(size_t)t * C_ + c0]) = nv;
}

// ----------------------------------------------------------- MFMA bf16 GEMM v3
// M=NTOK, N=256, K=kdim (256 or 512). BM=64, BN=256, BK=32; 4 waves, wave w
// owns cols [w*64, w*64+64), acc[4][4] (64 VGPR). One block per 64-row strip.
// A bf16 [M][256] (k<256); A2 second buffer for k in [256,512).
// B = g_wT[bofs]: bf16 B^T [256 n][kdim k].
// Staging via global_load_lds(16B) into lane-linear LDS, double-buffered,
// one barrier per K-step (T3 minimum 2-phase template).
// Epilogue: acc -> LDS transpose (per-wave 16x68 fp32 slice) -> coalesced
// stores: float4 RMW (mode 5) or 2x16B bf16 stores (modes 0/1/2).
// mode: 0 plain->Cm, 1 +bias->Cm, 2 +bias+GELU->Cm, 5 Cf += acc + bias.
// In-place safe (Cm/Cf aliasing A/A2): block reads only rows [row0,row0+64)
// (all in K-loop, before epilogue) and writes only those rows.
__global__ __launch_bounds__(256, 3) void gemm_v3_kernel(
    const u16* __restrict__ A, const u16* __restrict__ A2,
    int bofs, int kdim,
    u16* __restrict__ Cm, float* __restrict__ Cf, const float* __restrict__ bias,
    int mode)
{
    // per buffer (u16 elems): A tile [64][32] at 0 (2048), B tile [256][32] at 2048 (8192)
    __shared__ __align__(16) u16 lds[2 * 10240];   // 40 KiB
    const int tid  = threadIdx.x;
    const int lane = tid & 63, wave = tid >> 6;
    const int lr = lane & 15, lq = lane >> 4;
    const int row0 = blockIdx.x * 64;
    const u16* Bt = &g_wT[bofs];

    const int s_row = lane >> 2;          // 0..15 within a 16-row segment
    const int s_kel = (lane & 3) * 8;     // k-element offset within 32

    floatx4 acc[4][4] = {};
    const int NK = kdim >> 5;
    int cur = 0;

    // ---- stage one K-step into buffer buf (5x global_load_lds per thread)
    auto STAGE = [&](int buf, int ks) {
        const int k0 = ks << 5;
        const u16* Asrc = A;
        int ka = k0;
        if (k0 >= 256) { Asrc = A2; ka = k0 - 256; }
        u16* lb = &lds[buf * 10240];
        // A: segment = wave (16 rows); lane-linear: elem = wave*512 + lane*8
        GL16(&Asrc[(size_t)(row0 + wave * 16 + s_row) * 256 + ka + s_kel],
             lb + wave * 512 + lane * 8);
        // B: segments s = wave*4+c (16 B^T-rows each)
#pragma unroll
        for (int c = 0; c < 4; ++c) {
            const int s = wave * 4 + c;
            GL16(&Bt[(size_t)(s * 16 + s_row) * kdim + k0 + s_kel],
                 lb + 2048 + s * 512 + lane * 8);
        }
    };

    STAGE(0, 0);
    __syncthreads();                      // drains vmcnt; buf0 ready

    for (int ks = 0; ks < NK; ++ks) {
        if (ks + 1 < NK) STAGE(cur ^ 1, ks + 1);   // issue-early: flies under compute
        const u16* lb = &lds[cur * 10240];
        bf16x8 af[4], bfv[4];
#pragma unroll
        for (int mt = 0; mt < 4; ++mt)
            af[mt] = *reinterpret_cast<const bf16x8*>(lb + (mt * 16 + lr) * 32 + lq * 8);
#pragma unroll
        for (int nt = 0; nt < 4; ++nt)
            bfv[nt] = *reinterpret_cast<const bf16x8*>(
                lb + 2048 + (wave * 64 + nt * 16 + lr) * 32 + lq * 8);
#pragma unroll
        for (int mt = 0; mt < 4; ++mt)
#pragma unroll
            for (int nt = 0; nt < 4; ++nt)
                acc[mt][nt] = __builtin_amdgcn_mfma_f32_16x16x32_bf16(
                    af[mt], bfv[nt], acc[mt][nt], 0, 0, 0);
        __syncthreads();                  // drains next-stage vmcnt + barrier
        cur ^= 1;
    }

    // ---- epilogue: per-wave LDS transpose slice (16 rows x 68 fp32, 4 passes)
    float* tw = reinterpret_cast<float*>(&lds[0]) + wave * (16 * 68);
#pragma unroll
    for (int mt = 0; mt < 4; ++mt) {
        asm volatile("s_waitcnt lgkmcnt(0)" ::: "memory");   // WAR vs prev pass reads
        __builtin_amdgcn_sched_barrier(0);
#pragma unroll
        for (int nt = 0; nt < 4; ++nt) {
            const int col = wave * 64 + nt * 16 + lr;
            const float bs = (mode != 0) ? bias[col] : 0.0f;
#pragma unroll
            for (int r = 0; r < 4; ++r) {
                float v = acc[mt][nt][r] + bs;
                if (mode == 2) v = 0.5f * v * (1.0f + erff(v * 0.70710678118654752f));
                tw[(lq * 4 + r) * 68 + nt * 16 + lr] = v;
            }
        }
        asm volatile("s_waitcnt lgkmcnt(0)" ::: "memory");   // writes visible to wave
        __builtin_amdgcn_sched_barrier(0);
        const int rrow = lane >> 2, grp = lane & 3;
        const float* src = &tw[rrow * 68 + grp * 16];
        float4 f0 = *reinterpret_cast<const float4*>(src + 0);
        float4 f1 = *reinterpret_cast<const float4*>(src + 4);
        float4 f2 = *reinterpret_cast<const float4*>(src + 8);
        float4 f3 = *reinterpret_cast<const float4*>(src + 12);
        const size_t gofs = (size_t)(row0 + mt * 16 + rrow) * 256 + wave * 64 + grp * 16;
        if (mode == 5) {
            float4* cp = reinterpret_cast<float4*>(&Cf[gofs]);
            float4 c0 = cp[0], c1 = cp[1], c2 = cp[2], c3 = cp[3];
            c0.x += f0.x; c0.y += f0.y; c0.z += f0.z; c0.w += f0.w;
            c1.x += f1.x; c1.y += f1.y; c1.z += f1.z; c1.w += f1.w;
            c2.x += f2.x; c2.y += f2.y; c2.z += f2.z; c2.w += f2.w;
            c3.x += f3.x; c3.y += f3.y; c3.z += f3.z; c3.w += f3.w;
            cp[0] = c0; cp[1] = c1; cp[2] = c2; cp[3] = c3;
        } else {
            const float tf[16] = {f0.x, f0.y, f0.z, f0.w, f1.x, f1.y, f1.z, f1.w,
                                  f2.x, f2.y, f2.z, f2.w, f3.x, f3.y, f3.z, f3.w};
            u16x8 o0, o1;
#pragma unroll
            for (int j = 0; j < 8; ++j) { o0[j] = f2bf(tf[j]); o1[j] = f2bf(tf[j + 8]); }
            *reinterpret_cast<u16x8*>(&Cm[gofs])     = o0;
            *reinterpret_cast<u16x8*>(&Cm[gofs + 8]) = o1;
        }
    }
}

// -------------------------------------------------------------- attention
// MFMA version. block = (window wb, depth-slice i); 8 heads sequential.
// 64 q x 192 keys, hd=32. 4 waves: wave w owns q-rows [16w, 16w+16).
__global__ __launch_bounds__(256) void attn_kernel(
    u16* __restrict__ qo, const u16* __restrict__ kb, const u16* __restrict__ vb,
    const float* __restrict__ rpbp)
{
    __shared__ __align__(16) u16 qh[64][40];     // [q][c]
    __shared__ __align__(16) u16 kt[192][40];    // [key][c]
    __shared__ __align__(16) u16 vtt[32][200];   // [d][key]  (V^T)
    __shared__ __align__(16) u16 sp[64][200];    // [q][key]  (P, bf16)
    __shared__ float biasld[RPB_N + 1];          // rpb column for head h

    const int wb = blockIdx.x >> 2;
    const int i  = blockIdx.x & 3;
    const int tid = threadIdx.x;
    const int lane = tid & 63, wave = tid >> 6;
    const int lr = lane & 15, lq = lane >> 4;
    const size_t qbase = ((size_t)(wb * 256 + i * 64)) * C_;

    int relb[12][4];
    {
        const int q0 = wave * 16 + lq * 4;
#pragma unroll
        for (int r = 0; r < 4; ++r) {
            const int q = q0 + r;
            const int hq = q >> 3, wq_ = q & 7;
#pragma unroll
            for (int t = 0; t < 12; ++t) {
                const int kl = t * 16 + lr;
                const int nk = (kl < i * 64) ? kl : kl + 64;
                const int dk = nk >> 6, hk = (nk >> 3) & 7, wk = nk & 7;
                relb[t][r] = (i - dk + 3) * 225 + (hq - hk + 7) * 15 + (wq_ - wk + 7);
            }
        }
    }

    for (int h = 0; h < 8; ++h) {
        {
            const int row = tid >> 2, g = tid & 3;
            *reinterpret_cast<float4*>(&qh[row][g * 8]) =
                *reinterpret_cast<const float4*>(&qo[qbase + (size_t)row * C_ + h * 32 + g * 8]);
        }
#pragma unroll
        for (int t = 0; t < 3; ++t) {
            const int c = tid + t * 256;
            const int kl = c >> 2, g = c & 3;
            const int nk = (kl < i * 64) ? kl : kl + 64;
            const size_t base = ((size_t)(wb * 256 + nk)) * C_ + h * 32 + g * 8;
            *reinterpret_cast<float4*>(&kt[kl][g * 8]) =
                *reinterpret_cast<const float4*>(&kb[base]);
            u16x8 vv = *reinterpret_cast<const u16x8*>(&vb[base]);
#pragma unroll
            for (int j = 0; j < 8; ++j) vtt[g * 8 + j][kl] = vv[j];
        }
        for (int j = tid; j < RPB_N; j += 256) biasld[j] = rpbp[j * 8 + h];
        __syncthreads();

        floatx4 acc[12];
#pragma unroll
        for (int t = 0; t < 12; ++t) acc[t] = (floatx4){0.f, 0.f, 0.f, 0.f};
        {
            const bf16x8 af = *reinterpret_cast<const bf16x8*>(&qh[wave * 16 + lr][lq * 8]);
#pragma unroll
            for (int t = 0; t < 12; ++t) {
                const bf16x8 bfv = *reinterpret_cast<const bf16x8*>(&kt[t * 16 + lr][lq * 8]);
                acc[t] = __builtin_amdgcn_mfma_f32_16x16x32_bf16(af, bfv, acc[t], 0, 0, 0);
            }
        }

        float mrow[4] = {-1e30f, -1e30f, -1e30f, -1e30f};
#pragma unroll
        for (int t = 0; t < 12; ++t)
#pragma unroll
            for (int r = 0; r < 4; ++r) {
                const float v = fmaf(acc[t][r], QSCALE, biasld[relb[t][r]]);
                acc[t][r] = v;
                mrow[r] = fmaxf(mrow[r], v);
            }
#pragma unroll
        for (int off = 8; off >= 1; off >>= 1)
#pragma unroll
            for (int r = 0; r < 4; ++r)
                mrow[r] = fmaxf(mrow[r], __shfl_xor(mrow[r], off, 64));

        float srow[4] = {0.f, 0.f, 0.f, 0.f};
#pragma unroll
        for (int t = 0; t < 12; ++t)
#pragma unroll
            for (int r = 0; r < 4; ++r) {
                const float e = __expf(acc[t][r] - mrow[r]);
                acc[t][r] = e;
                srow[r] += e;
            }
#pragma unroll
        for (int off = 8; off >= 1; off >>= 1)
#pragma unroll
            for (int r = 0; r < 4; ++r)
                srow[r] += __shfl_xor(srow[r], off, 64);
#pragma unroll
        for (int r = 0; r < 4; ++r) srow[r] = 1.0f / srow[r];

#pragma unroll
        for (int t = 0; t < 12; ++t)
#pragma unroll
            for (int r = 0; r < 4; ++r)
                sp[wave * 16 + lq * 4 + r][t * 16 + lr] = f2bf(acc[t][r] * srow[r]);
        __syncthreads();

        floatx4 oacc[2];
        oacc[0] = (floatx4){0.f, 0.f, 0.f, 0.f};
        oacc[1] = (floatx4){0.f, 0.f, 0.f, 0.f};
#pragma unroll
        for (int kc = 0; kc < 6; ++kc) {
            const bf16x8 pa = *reinterpret_cast<const bf16x8*>(&sp[wave * 16 + lr][kc * 32 + lq * 8]);
#pragma unroll
            for (int nt = 0; nt < 2; ++nt) {
                const bf16x8 bv = *reinterpret_cast<const bf16x8*>(&vtt[nt * 16 + lr][kc * 32 + lq * 8]);
                oacc[nt] = __builtin_amdgcn_mfma_f32_16x16x32_bf16(pa, bv, oacc[nt], 0, 0, 0);
            }
        }
#pragma unroll
        for (int nt = 0; nt < 2; ++nt)
#pragma unroll
            for (int r = 0; r < 4; ++r)
                qo[qbase + (size_t)(wave * 16 + lq * 4 + r) * C_ + h * 32 + nt * 16 + lr] =
                    f2bf(oacc[nt][r]);
        __syncthreads();   // protect LDS restage next head
    }
}

// ----------------------------------------------------------------- launch
extern "C" void kernel_launch(void* const* d_in, const int* in_sizes, int n_in,
                              void* d_out, int out_size, void* d_ws, size_t ws_size,
                              hipStream_t stream) {
    const float* x    = (const float*)d_in[0];
    const float* ln1g = (const float*)d_in[1];
    const float* ln1b = (const float*)d_in[2];
    const float* ln2g = (const float*)d_in[3];
    const float* ln2b = (const float*)d_in[4];
    const float* wq   = (const float*)d_in[5];
    const float* wkv  = (const float*)d_in[6];
    const float* wp   = (const float*)d_in[7];
    const float* bp   = (const float*)d_in[8];
    const float* rpb  = (const float*)d_in[9];
    const float* w1   = (const float*)d_in[10];
    const float* b1   = (const float*)d_in[11];
    const float* w2   = (const float*)d_in[12];
    const float* b2   = (const float*)d_in[13];
    float* outf = (float*)d_out;
    u16*   outu = (u16*)d_out;          // bf16 scratch view: [k | v]
    u16*   ws16 = (u16*)d_ws;

    u16* r0 = ws16;                     // xw -> q -> o -> oproj -> h1
    u16* r1 = ws16 + R1_ELEMS;          // xn -> h2 (in-place)
    u16* kbuf = outu;
    u16* vbuf = outu + R1_ELEMS;

    // 0. convert weights to bf16 B^T into g_wT (once per launch; idempotent)
    wcvt_kernel<<<256, 256, 0, stream>>>(wq,  256, 8, 0);
    wcvt_kernel<<<512, 256, 0, stream>>>(wkv, 512, 8, 65536);
    wcvt_kernel<<<256, 256, 0, stream>>>(wp,  256, 8, 196608);
    wcvt_kernel<<<512, 256, 0, stream>>>(w1,  512, 8, 262144);
    wcvt_kernel<<<512, 256, 0, stream>>>(w2,  256, 9, 393216);

    // 1. LN1 + window partition (fp32 -> bf16)
    ln_part_kernel<<<NTOK / 4, 256, 0, stream>>>(x, ln1g, ln1b, r0);

    // 2. k, v = xw @ wkv halves -> d_out bf16 halves
    gemm_v3_kernel<<<NTOK / 64, 256, 0, stream>>>(r0, r0, 65536,  256, kbuf, nullptr, nullptr, 0);
    gemm_v3_kernel<<<NTOK / 64, 256, 0, stream>>>(r0, r0, 131072, 256, vbuf, nullptr, nullptr, 0);
    // 3. q = xw @ wq -> r0 (in-place)
    gemm_v3_kernel<<<NTOK / 64, 256, 0, stream>>>(r0, r0, 0, 256, r0, nullptr, nullptr, 0);

    // 4. attention: o overwrites q in r0
    attn_kernel<<<512 * 4, 256, 0, stream>>>(r0, kbuf, vbuf, rpb);

    // 5. oproj = o @ wp + bp -> r0 (in-place)
    gemm_v3_kernel<<<NTOK / 64, 256, 0, stream>>>(r0, r0, 196608, 256, r0, nullptr, bp, 1);

    // 6. y = x + reverse(oproj) -> d_out fp32 (k,v dead); xn = LN2(y) -> r1
    resid_ln2_kernel<<<NTOK / 4, 256, 0, stream>>>(x, r0, ln2g, ln2b, outf, r1);

    // 7. MLP: h1 -> r0 (oproj dead), h2 -> r1 in-place over xn,
    //    then single K=512 GEMM: out = y + [h1|h2] @ w2^T + b2 (fp32 RMW once)
    gemm_v3_kernel<<<NTOK / 64, 256, 0, stream>>>(r1, r1, 262144, 256, r0, nullptr, b1,       2);
    gemm_v3_kernel<<<NTOK / 64, 256, 0, stream>>>(r1, r1, 327680, 256, r1, nullptr, b1 + 256, 2);
    gemm_v3_kernel<<<NTOK / 64, 256, 0, stream>>>(r0, r1, 393216, 512, nullptr, outf, b2,     5);
}

// Round 4
// 924.289 us; speedup vs baseline: 3.9033x; 1.0398x over previous
//
#include <hip/hip_runtime.h>

typedef unsigned short u16;
typedef __bf16 bf16x8 __attribute__((ext_vector_type(8)));
typedef float floatx4 __attribute__((ext_vector_type(4)));
typedef unsigned short u16x8 __attribute__((ext_vector_type(8)));

#define C_  256
#define NTOK 131072                  // B*D*H*W = 8*4*64*64
#define QS2 0.25503488f              // 1/sqrt(32) * log2(e)
#define LOG2E 1.4426950408889634f

// ws: two bf16 regions of NTOK*256 elems.
// r0: xw -> q (in-place) -> o (in-place) -> oproj (in-place) -> h1
// r1: xn -> h2 (in-place)
// d_out: [k | vT] bf16 halves during attention, then y fp32 (RMW'd into out).
#define R1_ELEMS 33554432ull

// All weights, pre-converted to bf16 B^T, in a static device buffer (1 MB).
// offsets (u16 elems): wq 0, wkv 65536, wp 196608, w1 262144, w2 393216
__device__ u16 g_wT[524288];
// Precomputed attention bias (window-independent), pre-scaled by log2(e), bf16.
// layout: [i][h][wave][lq][lr][t][r]  = (((i*8+h)*256 + wave*64+lq*16+lr))*48 + t*4 + r
__device__ u16 g_bexp[393216];       // 4*8*64*192

__device__ __forceinline__ float bf2f(u16 u) {
    return __uint_as_float(((unsigned)u) << 16);
}
__device__ __forceinline__ u16 f2bf(float f) {
    unsigned u = __float_as_uint(f);
    return (u16)((u + 0x7FFFu + ((u >> 16) & 1u)) >> 16);  // RNE
}

// async global->LDS, 16B per lane. LDS dest is wave-uniform base + lane*16;
// our LDS layouts are lane-linear so dest == base + lane*16 by construction.
#define GL16(gsrc, ldst) __builtin_amdgcn_global_load_lds(                    \
    (const __attribute__((address_space(1))) void*)(gsrc),                    \
    (__attribute__((address_space(3))) void*)(ldst), 16, 0, 0)

// ------------------------------------------------- weight convert fp32->bf16 B^T
// W fp32 [Kd][N] row-major -> g_wT[ofs + n*Kd + k], Kd = 1<<ks.
__global__ __launch_bounds__(256) void wcvt_kernel(
    const float* __restrict__ W, int N, int ks, int ofs)
{
    const int idx = blockIdx.x * 256 + threadIdx.x;
    const int n = idx >> ks;
    const int k = idx & ((1 << ks) - 1);
    g_wT[ofs + idx] = f2bf(W[(size_t)k * N + n]);
}

// ------------------------------------------------- bias expand (once)
// grid 32 = (i*8+h). Per (i,h): fill per-lane-contiguous [wave][lq][lr][t][r].
__global__ __launch_bounds__(256) void bexp_kernel(const float* __restrict__ rpb)
{
    const int i = blockIdx.x >> 3, h = blockIdx.x & 7;
    const int tf = threadIdx.x;
    const int w = tf >> 6, lq = (tf >> 4) & 3, lr = tf & 15;
    u16* dst = &g_bexp[((size_t)(blockIdx.x * 256 + tf)) * 48];
#pragma unroll
    for (int t = 0; t < 12; ++t) {
        const int kl = t * 16 + lr;
        const int nk = (kl < i * 64) ? kl : kl + 64;
        const int dk = nk >> 6, hk = (nk >> 3) & 7, wk = nk & 7;
#pragma unroll
        for (int r = 0; r < 4; ++r) {
            const int q = w * 16 + lq * 4 + r;
            const int hq = q >> 3, wq = q & 7;
            const int rel = (i - dk + 3) * 225 + (hq - hk + 7) * 15 + (wq - wk + 7);
            dst[t * 4 + r] = f2bf(rpb[rel * 8 + h] * LOG2E);
        }
    }
}

// ---------------------------------------------------------- LN1 + partition
__global__ __launch_bounds__(256) void ln_part_kernel(
    const float* __restrict__ x, const float* __restrict__ g, const float* __restrict__ bb,
    u16* __restrict__ xw)
{
    const int lane = threadIdx.x & 63;
    const int wave = threadIdx.x >> 6;
    const int t = blockIdx.x * 4 + wave;          // window row: wb*256+n
    const int wb = t >> 8, n = t & 255;
    const int bidx = wb >> 6, hb = (wb >> 3) & 7, wbl = wb & 7;
    const int d = n >> 6, hh = (n >> 3) & 7, ww = n & 7;
    const size_t src = ((((size_t)bidx * 4 + d) * 64 + hb * 8 + hh) * 64 + wbl * 8 + ww) * C_;
    const int c0 = lane * 4;
    float4 raw = *reinterpret_cast<const float4*>(&x[src + c0]);
    float v0 = raw.x, v1 = raw.y, v2 = raw.z, v3 = raw.w;
    float s = v0 + v1 + v2 + v3;
    float sq = v0 * v0 + v1 * v1 + v2 * v2 + v3 * v3;
#pragma unroll
    for (int off = 32; off > 0; off >>= 1) {
        s  += __shfl_xor(s, off, 64);
        sq += __shfl_xor(sq, off, 64);
    }
    const float mean = s * (1.0f / 256.0f);
    const float var  = sq * (1.0f / 256.0f) - mean * mean;
    const float rstd = rsqrtf(var + 1e-5f);
    float4 gr = *reinterpret_cast<const float4*>(&g[c0]);
    float4 br = *reinterpret_cast<const float4*>(&bb[c0]);
    ushort4 outv;
    outv.x = f2bf((v0 - mean) * rstd * gr.x + br.x);
    outv.y = f2bf((v1 - mean) * rstd * gr.y + br.y);
    outv.z = f2bf((v2 - mean) * rstd * gr.z + br.z);
    outv.w = f2bf((v3 - mean) * rstd * gr.w + br.w);
    *reinterpret_cast<ushort4*>(&xw[(size_t)t * C_ + c0]) = outv;
}

// ------------------------------------------------- residual + LN2
__global__ __launch_bounds__(256) void resid_ln2_kernel(
    const float* __restrict__ x, const u16* __restrict__ oproj,
    const float* __restrict__ g, const float* __restrict__ bb,
    float* __restrict__ y, u16* __restrict__ xn)
{
    const int lane = threadIdx.x & 63;
    const int wave = threadIdx.x >> 6;
    const int t = blockIdx.x * 4 + wave;          // x-layout token
    const int wpos = t & 63;
    const int h = (t >> 6) & 63;
    const int d = (t >> 12) & 3;
    const int bidx = t >> 14;
    const int wr = (((bidx * 8) + (h >> 3)) * 8 + (wpos >> 3)) * 256
                 + d * 64 + (h & 7) * 8 + (wpos & 7);   // window row
    const int c0 = lane * 4;
    float4 xr = *reinterpret_cast<const float4*>(&x[(size_t)t * C_ + c0]);
    ushort4 pr = *reinterpret_cast<const ushort4*>(&oproj[(size_t)wr * C_ + c0]);
    float v0 = xr.x + bf2f(pr.x);
    float v1 = xr.y + bf2f(pr.y);
    float v2 = xr.z + bf2f(pr.z);
    float v3 = xr.w + bf2f(pr.w);
    float s = v0 + v1 + v2 + v3;
    float sq = v0 * v0 + v1 * v1 + v2 * v2 + v3 * v3;
#pragma unroll
    for (int off = 32; off > 0; off >>= 1) {
        s  += __shfl_xor(s, off, 64);
        sq += __shfl_xor(sq, off, 64);
    }
    const float mean = s * (1.0f / 256.0f);
    const float var  = sq * (1.0f / 256.0f) - mean * mean;
    const float rstd = rsqrtf(var + 1e-5f);
    float4 yv; yv.x = v0; yv.y = v1; yv.z = v2; yv.w = v3;
    *reinterpret_cast<float4*>(&y[(size_t)t * C_ + c0]) = yv;
    float4 gr = *reinterpret_cast<const float4*>(&g[c0]);
    float4 br = *reinterpret_cast<const float4*>(&bb[c0]);
    ushort4 nv;
    nv.x = f2bf((v0 - mean) * rstd * gr.x + br.x);
    nv.y = f2bf((v1 - mean) * rstd * gr.y + br.y);
    nv.z = f2bf((v2 - mean) * rstd * gr.z + br.z);
    nv.w = f2bf((v3 - mean) * rstd * gr.w + br.w);
    *reinterpret_cast<ushort4*>(&xn[(size_t)t * C_ + c0]) = nv;
}

// ----------------------------------------------------------- MFMA bf16 GEMM v3
// M=NTOK, N=256, K=kdim (256 or 512). BM=64, BN=256, BK=32; 4 waves, wave w
// owns cols [w*64, w*64+64), acc[4][4]. One block per 64-row strip.
// mode: 0 plain->Cm, 1 +bias->Cm, 2 +bias+GELU->Cm, 5 Cf += acc + bias,
//       7 transposed store: Cm is [256][NTOK], Cm[col][row] = bf16(acc).
__global__ __launch_bounds__(256, 3) void gemm_v3_kernel(
    const u16* __restrict__ A, const u16* __restrict__ A2,
    int bofs, int kdim,
    u16* __restrict__ Cm, float* __restrict__ Cf, const float* __restrict__ bias,
    int mode)
{
    // per buffer (u16 elems): A tile [64][32] at 0 (2048), B tile [256][32] at 2048 (8192)
    __shared__ __align__(16) u16 lds[2 * 10240];   // 40 KiB
    const int tid  = threadIdx.x;
    const int lane = tid & 63, wave = tid >> 6;
    const int lr = lane & 15, lq = lane >> 4;
    const int row0 = blockIdx.x * 64;
    const u16* Bt = &g_wT[bofs];

    const int s_row = lane >> 2;          // 0..15 within a 16-row segment
    const int s_kel = (lane & 3) * 8;     // k-element offset within 32

    floatx4 acc[4][4] = {};
    const int NK = kdim >> 5;
    int cur = 0;

    // ---- stage one K-step into buffer buf (5x global_load_lds per thread)
    auto STAGE = [&](int buf, int ks) {
        const int k0 = ks << 5;
        const u16* Asrc = A;
        int ka = k0;
        if (k0 >= 256) { Asrc = A2; ka = k0 - 256; }
        u16* lb = &lds[buf * 10240];
        // A: segment = wave (16 rows); lane-linear: elem = wave*512 + lane*8
        GL16(&Asrc[(size_t)(row0 + wave * 16 + s_row) * 256 + ka + s_kel],
             lb + wave * 512 + lane * 8);
        // B: segments s = wave*4+c (16 B^T-rows each)
#pragma unroll
        for (int c = 0; c < 4; ++c) {
            const int s = wave * 4 + c;
            GL16(&Bt[(size_t)(s * 16 + s_row) * kdim + k0 + s_kel],
                 lb + 2048 + s * 512 + lane * 8);
        }
    };

    STAGE(0, 0);
    __syncthreads();                      // drains vmcnt; buf0 ready

    for (int ks = 0; ks < NK; ++ks) {
        if (ks + 1 < NK) STAGE(cur ^ 1, ks + 1);   // issue-early: flies under compute
        const u16* lb = &lds[cur * 10240];
        bf16x8 af[4], bfv[4];
#pragma unroll
        for (int mt = 0; mt < 4; ++mt)
            af[mt] = *reinterpret_cast<const bf16x8*>(lb + (mt * 16 + lr) * 32 + lq * 8);
#pragma unroll
        for (int nt = 0; nt < 4; ++nt)
            bfv[nt] = *reinterpret_cast<const bf16x8*>(
                lb + 2048 + (wave * 64 + nt * 16 + lr) * 32 + lq * 8);
#pragma unroll
        for (int mt = 0; mt < 4; ++mt)
#pragma unroll
            for (int nt = 0; nt < 4; ++nt)
                acc[mt][nt] = __builtin_amdgcn_mfma_f32_16x16x32_bf16(
                    af[mt], bfv[nt], acc[mt][nt], 0, 0, 0);
        __syncthreads();                  // drains next-stage vmcnt + barrier
        cur ^= 1;
    }

    if (mode == 7) {
        // transposed bf16 store, direct from acc (8B per (mt,nt))
#pragma unroll
        for (int mt = 0; mt < 4; ++mt)
#pragma unroll
            for (int nt = 0; nt < 4; ++nt) {
                const int col = wave * 64 + nt * 16 + lr;
                const size_t tok = (size_t)row0 + mt * 16 + lq * 4;
                ushort4 st;
                st.x = f2bf(acc[mt][nt][0]);
                st.y = f2bf(acc[mt][nt][1]);
                st.z = f2bf(acc[mt][nt][2]);
                st.w = f2bf(acc[mt][nt][3]);
                *reinterpret_cast<ushort4*>(&Cm[(size_t)col * NTOK + tok]) = st;
            }
        return;
    }

    // ---- epilogue: per-wave LDS transpose slice (16 rows x 68 fp32, 4 passes)
    float* tw = reinterpret_cast<float*>(&lds[0]) + wave * (16 * 68);
#pragma unroll
    for (int mt = 0; mt < 4; ++mt) {
        asm volatile("s_waitcnt lgkmcnt(0)" ::: "memory");   // WAR vs prev pass reads
        __builtin_amdgcn_sched_barrier(0);
#pragma unroll
        for (int nt = 0; nt < 4; ++nt) {
            const int col = wave * 64 + nt * 16 + lr;
            const float bs = (mode != 0) ? bias[col] : 0.0f;
#pragma unroll
            for (int r = 0; r < 4; ++r) {
                float v = acc[mt][nt][r] + bs;
                if (mode == 2) v = 0.5f * v * (1.0f + erff(v * 0.70710678118654752f));
                tw[(lq * 4 + r) * 68 + nt * 16 + lr] = v;
            }
        }
        asm volatile("s_waitcnt lgkmcnt(0)" ::: "memory");   // writes visible to wave
        __builtin_amdgcn_sched_barrier(0);
        const int rrow = lane >> 2, grp = lane & 3;
        const float* src = &tw[rrow * 68 + grp * 16];
        float4 f0 = *reinterpret_cast<const float4*>(src + 0);
        float4 f1 = *reinterpret_cast<const float4*>(src + 4);
        float4 f2 = *reinterpret_cast<const float4*>(src + 8);
        float4 f3 = *reinterpret_cast<const float4*>(src + 12);
        const size_t gofs = (size_t)(row0 + mt * 16 + rrow) * 256 + wave * 64 + grp * 16;
        if (mode == 5) {
            float4* cp = reinterpret_cast<float4*>(&Cf[gofs]);
            float4 c0 = cp[0], c1 = cp[1], c2 = cp[2], c3 = cp[3];
            c0.x += f0.x; c0.y += f0.y; c0.z += f0.z; c0.w += f0.w;
            c1.x += f1.x; c1.y += f1.y; c1.z += f1.z; c1.w += f1.w;
            c2.x += f2.x; c2.y += f2.y; c2.z += f2.z; c2.w += f2.w;
            c3.x += f3.x; c3.y += f3.y; c3.z += f3.z; c3.w += f3.w;
            cp[0] = c0; cp[1] = c1; cp[2] = c2; cp[3] = c3;
        } else {
            const float tf[16] = {f0.x, f0.y, f0.z, f0.w, f1.x, f1.y, f1.z, f1.w,
                                  f2.x, f2.y, f2.z, f2.w, f3.x, f3.y, f3.z, f3.w};
            u16x8 o0, o1;
#pragma unroll
            for (int j = 0; j < 8; ++j) { o0[j] = f2bf(tf[j]); o1[j] = f2bf(tf[j + 8]); }
            *reinterpret_cast<u16x8*>(&Cm[gofs])     = o0;
            *reinterpret_cast<u16x8*>(&Cm[gofs + 8]) = o1;
        }
    }
}

// -------------------------------------------------------------- attention v2
// Barrier-free. block = (window wb, slice i), XCD-swizzled so a window's 4
// slice-blocks share one XCD's L2. 4 waves; wave w owns q-rows [16w,16w+16).
// All MFMA fragments read directly from global (L2): Q/K rows, V^T rows
// (produced transposed by GEMM mode 7). Bias from g_bexp (6x16B per lane).
// Softmax in log2 domain. Only LDS: wave-private P roundtrip (C/D->A frag).
__global__ __launch_bounds__(256, 3) void attn_kernel(
    u16* __restrict__ qo, const u16* __restrict__ kb, const u16* __restrict__ vT)
{
    __shared__ __align__(16) u16 sp[64][200];    // [q][key] P, bf16 (wave-private rows)

    const int bid = blockIdx.x;
    const int i  = (bid >> 3) & 3;
    const int wb = (bid & 7) + (bid >> 5) * 8;   // XCD = wb % 8
    const int tid = threadIdx.x;
    const int lane = tid & 63, wave = tid >> 6;
    const int lr = lane & 15, lq = lane >> 4;
    const size_t qbase = ((size_t)(wb * 256 + i * 64)) * C_;
    const size_t kwin  = ((size_t)(wb * 256)) * C_;
    const u16* bx = &g_bexp[((size_t)((i * 8) * 256) + (size_t)(wave * 64 + lq * 16 + lr)) * 48];

    for (int h = 0; h < 8; ++h) {
        const int hc = h * 32;
        // ---- bias fragment: 48 bf16 contiguous per lane
        u16x8 bvv[6];
        {
            const u16* bl = bx + (size_t)h * 256 * 48;
#pragma unroll
            for (int v = 0; v < 6; ++v)
                bvv[v] = *reinterpret_cast<const u16x8*>(bl + v * 8);
        }
        // ---- QK^T: A = own q rows, B = key rows (12 tiles), direct global
        const bf16x8 af = *reinterpret_cast<const bf16x8*>(
            &qo[qbase + (size_t)(wave * 16 + lr) * C_ + hc + lq * 8]);
        floatx4 acc[12];
#pragma unroll
        for (int t = 0; t < 12; ++t) {
            const int nrow = t * 16 + ((t * 16 >= i * 64) ? 64 : 0) + lr;
            const bf16x8 bk = *reinterpret_cast<const bf16x8*>(
                &kb[kwin + (size_t)nrow * C_ + hc + lq * 8]);
            acc[t] = __builtin_amdgcn_mfma_f32_16x16x32_bf16(
                af, bk, (floatx4){0.f, 0.f, 0.f, 0.f}, 0, 0, 0);
        }
        // ---- scale (log2 domain) + bias, row max
        float mrow[4] = {-1e30f, -1e30f, -1e30f, -1e30f};
#pragma unroll
        for (int t = 0; t < 12; ++t)
#pragma unroll
            for (int r = 0; r < 4; ++r) {
                const int ii = t * 4 + r;
                const float v = fmaf(acc[t][r], QS2, bf2f((u16)bvv[ii >> 3][ii & 7]));
                acc[t][r] = v;
                mrow[r] = fmaxf(mrow[r], v);
            }
#pragma unroll
        for (int off = 8; off >= 1; off >>= 1)
#pragma unroll
            for (int r = 0; r < 4; ++r)
                mrow[r] = fmaxf(mrow[r], __shfl_xor(mrow[r], off, 64));
        // ---- exp2 + row sum
        float srow[4] = {0.f, 0.f, 0.f, 0.f};
#pragma unroll
        for (int t = 0; t < 12; ++t)
#pragma unroll
            for (int r = 0; r < 4; ++r) {
                const float e = exp2f(acc[t][r] - mrow[r]);
                acc[t][r] = e;
                srow[r] += e;
            }
#pragma unroll
        for (int off = 8; off >= 1; off >>= 1)
#pragma unroll
            for (int r = 0; r < 4; ++r)
                srow[r] += __shfl_xor(srow[r], off, 64);
#pragma unroll
        for (int r = 0; r < 4; ++r) srow[r] = 1.0f / srow[r];
        // ---- P -> LDS (wave-private rows; no barrier needed)
#pragma unroll
        for (int t = 0; t < 12; ++t)
#pragma unroll
            for (int r = 0; r < 4; ++r)
                sp[wave * 16 + lq * 4 + r][t * 16 + lr] = f2bf(acc[t][r] * srow[r]);
        // ---- PV: A = P rows (LDS), B = V^T rows (direct global)
        floatx4 oacc[2];
        oacc[0] = (floatx4){0.f, 0.f, 0.f, 0.f};
        oacc[1] = (floatx4){0.f, 0.f, 0.f, 0.f};
#pragma unroll
        for (int kc = 0; kc < 6; ++kc) {
            const bf16x8 pa = *reinterpret_cast<const bf16x8*>(
                &sp[wave * 16 + lr][kc * 32 + lq * 8]);
            const int kst = kc * 32 + lq * 8;
            const int nk0 = kst + ((kst >= i * 64) ? 64 : 0);
#pragma unroll
            for (int nt = 0; nt < 2; ++nt) {
                const bf16x8 bv = *reinterpret_cast<const bf16x8*>(
                    &vT[(size_t)(hc + nt * 16 + lr) * NTOK + wb * 256 + nk0]);
                oacc[nt] = __builtin_amdgcn_mfma_f32_16x16x32_bf16(pa, bv, oacc[nt], 0, 0, 0);
            }
        }
        // ---- write O over q columns for head h
#pragma unroll
        for (int nt = 0; nt < 2; ++nt)
#pragma unroll
            for (int r = 0; r < 4; ++r)
                qo[qbase + (size_t)(wave * 16 + lq * 4 + r) * C_ + hc + nt * 16 + lr] =
                    f2bf(oacc[nt][r]);
    }
}

// ----------------------------------------------------------------- launch
extern "C" void kernel_launch(void* const* d_in, const int* in_sizes, int n_in,
                              void* d_out, int out_size, void* d_ws, size_t ws_size,
                              hipStream_t stream) {
    const float* x    = (const float*)d_in[0];
    const float* ln1g = (const float*)d_in[1];
    const float* ln1b = (const float*)d_in[2];
    const float* ln2g = (const float*)d_in[3];
    const float* ln2b = (const float*)d_in[4];
    const float* wq   = (const float*)d_in[5];
    const float* wkv  = (const float*)d_in[6];
    const float* wp   = (const float*)d_in[7];
    const float* bp   = (const float*)d_in[8];
    const float* rpb  = (const float*)d_in[9];
    const float* w1   = (const float*)d_in[10];
    const float* b1   = (const float*)d_in[11];
    const float* w2   = (const float*)d_in[12];
    const float* b2   = (const float*)d_in[13];
    float* outf = (float*)d_out;
    u16*   outu = (u16*)d_out;          // bf16 scratch view: [k | vT]
    u16*   ws16 = (u16*)d_ws;

    u16* r0 = ws16;                     // xw -> q -> o -> oproj -> h1
    u16* r1 = ws16 + R1_ELEMS;          // xn -> h2 (in-place)
    u16* kbuf = outu;
    u16* vTb  = outu + R1_ELEMS;        // V^T [256][NTOK]

    // 0. convert weights to bf16 B^T into g_wT; expand bias table (once per launch)
    wcvt_kernel<<<256, 256, 0, stream>>>(wq,  256, 8, 0);
    wcvt_kernel<<<512, 256, 0, stream>>>(wkv, 512, 8, 65536);
    wcvt_kernel<<<256, 256, 0, stream>>>(wp,  256, 8, 196608);
    wcvt_kernel<<<512, 256, 0, stream>>>(w1,  512, 8, 262144);
    wcvt_kernel<<<512, 256, 0, stream>>>(w2,  256, 9, 393216);
    bexp_kernel<<<32, 256, 0, stream>>>(rpb);

    // 1. LN1 + window partition (fp32 -> bf16)
    ln_part_kernel<<<NTOK / 4, 256, 0, stream>>>(x, ln1g, ln1b, r0);

    // 2. k = xw @ wkv[:,0:256] -> kbuf; v^T = (xw @ wkv[:,256:512])^T -> vTb
    gemm_v3_kernel<<<NTOK / 64, 256, 0, stream>>>(r0, r0, 65536,  256, kbuf, nullptr, nullptr, 0);
    gemm_v3_kernel<<<NTOK / 64, 256, 0, stream>>>(r0, r0, 131072, 256, vTb,  nullptr, nullptr, 7);
    // 3. q = xw @ wq -> r0 (in-place)
    gemm_v3_kernel<<<NTOK / 64, 256, 0, stream>>>(r0, r0, 0, 256, r0, nullptr, nullptr, 0);

    // 4. attention: o overwrites q in r0 (barrier-free, XCD-swizzled)
    attn_kernel<<<2048, 256, 0, stream>>>(r0, kbuf, vTb);

    // 5. oproj = o @ wp + bp -> r0 (in-place)
    gemm_v3_kernel<<<NTOK / 64, 256, 0, stream>>>(r0, r0, 196608, 256, r0, nullptr, bp, 1);

    // 6. y = x + reverse(oproj) -> d_out fp32 (k,vT dead); xn = LN2(y) -> r1
    resid_ln2_kernel<<<NTOK / 4, 256, 0, stream>>>(x, r0, ln2g, ln2b, outf, r1);

    // 7. MLP: h1 -> r0 (oproj dead), h2 -> r1 in-place over xn,
    //    then single K=512 GEMM: out = y + [h1|h2] @ w2^T + b2 (fp32 RMW once)
    gemm_v3_kernel<<<NTOK / 64, 256, 0, stream>>>(r1, r1, 262144, 256, r0, nullptr, b1,       2);
    gemm_v3_kernel<<<NTOK / 64, 256, 0, stream>>>(r1, r1, 327680, 256, r1, nullptr, b1 + 256, 2);
    gemm_v3_kernel<<<NTOK / 64, 256, 0, stream>>>(r0, r1, 393216, 512, nullptr, outf, b2,     5);
}